// Round 8
// baseline (233.692 us; speedup 1.0000x reference)
//
#include <hip/hip_runtime.h>
#include <hip/hip_bf16.h>

#define V_     32000
#define NSEG_  2
#define MAXLEN_ 512
#define D_     768
#define H_     12
#define HS_    64
#define B_     16
#define T_     512
#define NMASK_ 20
#define LN_EPS_ 1e-5f

typedef __hip_bfloat16 bf16;
typedef unsigned short ushortT;
typedef __attribute__((ext_vector_type(8))) short short8;
typedef __attribute__((ext_vector_type(4))) float f32x4;
typedef __attribute__((ext_vector_type(4))) unsigned int u32x4;

__device__ __forceinline__ ushortT f2bu(float f) {
    bf16 h = __float2bfloat16(f);
    return *reinterpret_cast<ushortT*>(&h);
}

// ---------------- Kernel 1: embedding gather + LayerNorm -> xb (bf16) ----------------
__global__ void k_embed_ln(const int* __restrict__ seq, const int* __restrict__ seg,
                           const float* __restrict__ tok, const float* __restrict__ sege,
                           const float* __restrict__ pos, const float* __restrict__ g,
                           const float* __restrict__ bb, ushortT* __restrict__ xb) {
    int row = blockIdx.x;          // b*T + t
    int t = row % T_;
    int tid = threadIdx.x;
    __shared__ float sbuf[D_];
    __shared__ float wsum[4], wsq[4];

    int sidx = seq[row];
    int gidx = seg[row];

    float lsum = 0.f, lsq = 0.f;
    for (int j = tid; j < D_; j += 256) {
        float e = tok[(size_t)sidx * D_ + j] + sege[(size_t)gidx * D_ + j] + pos[(size_t)t * D_ + j];
        sbuf[j] = e;
        lsum += e;
        lsq  += e * e;
    }
    #pragma unroll
    for (int o = 32; o > 0; o >>= 1) {
        lsum += __shfl_down(lsum, o);
        lsq  += __shfl_down(lsq, o);
    }
    if ((tid & 63) == 0) { wsum[tid >> 6] = lsum; wsq[tid >> 6] = lsq; }
    __syncthreads();
    float s  = wsum[0] + wsum[1] + wsum[2] + wsum[3];
    float sq = wsq[0] + wsq[1] + wsq[2] + wsq[3];
    float mean = s * (1.0f / D_);
    float var  = sq * (1.0f / D_) - mean * mean;
    float rstd = rsqrtf(var + LN_EPS_);
    for (int j = tid; j < D_; j += 256) {
        xb[(size_t)row * D_ + j] = f2bu((sbuf[j] - mean) * rstd * g[j] + bb[j]);
    }
}

// ---------------- Prep: WcatT[n][k] bf16, n = which*768 + h*64 + s ----------------
__global__ void k_prep_wqkv(const float* __restrict__ Wq, const float* __restrict__ Wk,
                            const float* __restrict__ Wv, ushortT* __restrict__ Wt) {
    int blk = blockIdx.x;
    int which = blk / H_, h = blk % H_;
    const float* W = (which == 0) ? Wq : (which == 1) ? Wk : Wv;  // [H][D][HS]
    __shared__ float tile[64][65];
    int tid = threadIdx.x, c = tid & 63, rgrp = tid >> 6;
    for (int kc = 0; kc < D_; kc += 64) {
        for (int kk = rgrp; kk < 64; kk += 4)
            tile[kk][c] = W[((size_t)h * D_ + kc + kk) * HS_ + c];
        __syncthreads();
        for (int ss = rgrp; ss < 64; ss += 4)
            Wt[((size_t)which * D_ + h * HS_ + ss) * D_ + kc + c] = f2bu(tile[c][ss]);
        __syncthreads();
    }
}

// ---------------- Prep: WlmT[v][d] bf16 from Wlm[d][v] f32 ----------------
__global__ void k_transpose_lm(const float* __restrict__ W, ushortT* __restrict__ Wt) {
    __shared__ float tile[64][65];
    int v0 = blockIdx.x * 64, d0 = blockIdx.y * 64;
    int tid = threadIdx.x, c = tid & 63;
    for (int rr = tid >> 6; rr < 64; rr += 4)
        tile[rr][c] = W[(size_t)(d0 + rr) * V_ + v0 + c];
    __syncthreads();
    for (int rr = tid >> 6; rr < 64; rr += 4)
        Wt[(size_t)(v0 + rr) * D_ + d0 + c] = f2bu(tile[c][rr]);
}

// ---------------- Prep: gather masked rows -> xm[384][768] bf16 (zero pad) ----------------
__global__ void k_gather_xm(const float* __restrict__ x2, const int* __restrict__ masked_pos,
                            ushortT* __restrict__ xm) {
    int r = blockIdx.x;      // 0..383
    int tid = threadIdx.x;
    if (r < B_ * NMASK_) {
        int b = r / NMASK_, m = r % NMASK_;
        int t = masked_pos[b * NMASK_ + m];
        for (int d = tid; d < D_; d += 256)
            xm[(size_t)r * D_ + d] = f2bu(x2[((size_t)b * T_ + t) * D_ + d]);
    } else {
        for (int d = tid; d < D_; d += 256)
            xm[(size_t)r * D_ + d] = 0;
    }
}

// ---------------- 2-phase double-buffered MFMA 128x128 GEMM body ----------------
// T3 "minimum 2-phase": STAGE(next) -> ds_read+MFMA(cur) -> vmcnt(0)+s_barrier.
// One barrier per K-step; next-tile global_load_lds overlaps the MFMA cluster.
// LDS layout (linear, gload_lds requirement): buf0 = As0[4096] Bs0[4096], buf1 at +8192.
__device__ __forceinline__ void stage_tile(const ushortT* __restrict__ A,
                                           const ushortT* __restrict__ Bt,
                                           int m0, int n0, int k0,
                                           ushortT* As, ushortT* Bs,
                                           int w, int lane) {
    #pragma unroll
    for (int i = 0; i < 2; ++i) {
        int slot = w * 64 + lane + i * 256;    // 0..511
        int row = slot >> 2, col = (slot & 3) * 8;
        __builtin_amdgcn_global_load_lds(
            (const __attribute__((address_space(1))) void*)(A + (size_t)(m0 + row) * D_ + k0 + col),
            (__attribute__((address_space(3))) void*)(As + (w * 64 + i * 256) * 8),
            16, 0, 0);
        __builtin_amdgcn_global_load_lds(
            (const __attribute__((address_space(1))) void*)(Bt + (size_t)(n0 + row) * D_ + k0 + col),
            (__attribute__((address_space(3))) void*)(Bs + (w * 64 + i * 256) * 8),
            16, 0, 0);
    }
}

__device__ __forceinline__ void gemm128_2ph(const ushortT* __restrict__ A,
                                            const ushortT* __restrict__ Bt,
                                            int m0, int n0,
                                            ushortT* lds,       // 16384 ushorts (32 KB)
                                            f32x4 acc[4][4]) {
    const int NT = D_ / 32;   // 24
    int tid = threadIdx.x;
    int lane = tid & 63, w = tid >> 6;
    int wr = (w >> 1) * 64, wc = (w & 1) * 64;
    int l16 = lane & 15, lk = lane >> 4;

    #pragma unroll
    for (int i = 0; i < 4; ++i)
        #pragma unroll
        for (int j = 0; j < 4; ++j)
            acc[i][j] = (f32x4){0.f, 0.f, 0.f, 0.f};

    // prologue: stage tile 0 into buf0, wait, barrier
    stage_tile(A, Bt, m0, n0, 0, lds, lds + 4096, w, lane);
    asm volatile("s_waitcnt vmcnt(0)" ::: "memory");
    __builtin_amdgcn_s_barrier();

    for (int t = 0; t < NT; ++t) {
        int cur = (t & 1) * 8192;
        int nxt = 8192 - cur;
        if (t + 1 < NT)
            stage_tile(A, Bt, m0, n0, (t + 1) * 32, lds + nxt, lds + nxt + 4096, w, lane);

        const ushortT* Asc = lds + cur;
        const ushortT* Bsc = lds + cur + 4096;
        short8 a[4], bfr[4];
        #pragma unroll
        for (int i = 0; i < 4; ++i) {
            a[i]   = *(const short8*)(Asc + (wr + i * 16 + l16) * 32 + lk * 8);
            bfr[i] = *(const short8*)(Bsc + (wc + i * 16 + l16) * 32 + lk * 8);
        }
        #pragma unroll
        for (int i = 0; i < 4; ++i)
            #pragma unroll
            for (int j = 0; j < 4; ++j)
                acc[i][j] = __builtin_amdgcn_mfma_f32_16x16x32_bf16(a[i], bfr[j], acc[i][j], 0, 0, 0);

        // only next-tile loads are outstanding here; they've had the MFMA cluster to land
        asm volatile("s_waitcnt vmcnt(0)" ::: "memory");
        __builtin_amdgcn_s_barrier();
    }
}

// ---------------- QKV GEMM: [8192 x 2304]; V written pre-transposed vt[bh][d][t] ----------------
__global__ __launch_bounds__(256, 4)
void k_gemm_qkv(const ushortT* __restrict__ xb, const ushortT* __restrict__ WcatT,
                ushortT* __restrict__ qb, ushortT* __restrict__ kb,
                ushortT* __restrict__ vt) {
    __shared__ ushortT lds[16384];
    f32x4 acc[4][4];
    int n0 = blockIdx.x * 128, m0 = blockIdx.y * 128;
    gemm128_2ph(xb, WcatT, m0, n0, lds, acc);

    int lane = threadIdx.x & 63, w = threadIdx.x >> 6;
    int wr = (w >> 1) * 64, wc = (w & 1) * 64;
    int l16 = lane & 15, lk = lane >> 4;
    #pragma unroll
    for (int j = 0; j < 4; ++j) {
        int n = n0 + wc + j * 16 + l16;
        int which = n / D_;          // uniform per block (128 | 768)
        int rem = n - which * D_;
        int h = rem >> 6, s = rem & 63;
        #pragma unroll
        for (int i = 0; i < 4; ++i) {
            #pragma unroll
            for (int r = 0; r < 4; ++r) {
                int m = m0 + wr + i * 16 + lk * 4 + r;
                int b = m >> 9, t = m & (T_ - 1);
                if (which == 2) {
                    vt[((size_t)(b * H_ + h) * HS_ + s) * T_ + t] = f2bu(acc[i][j][r]);
                } else {
                    ushortT* outp = (which == 0) ? qb : kb;
                    outp[((size_t)(b * H_ + h) * T_ + t) * HS_ + s] = f2bu(acc[i][j][r]);
                }
            }
        }
    }
}

// ---------------- LM GEMM: [384 x 32000] ----------------
__global__ __launch_bounds__(256, 4)
void k_gemm_lm(const ushortT* __restrict__ xm, const ushortT* __restrict__ WlmT,
               const float* __restrict__ blm, float* __restrict__ out) {
    __shared__ ushortT lds[16384];
    f32x4 acc[4][4];
    int m0 = blockIdx.x * 128, n0 = blockIdx.y * 128;
    gemm128_2ph(xm, WlmT, m0, n0, lds, acc);

    int lane = threadIdx.x & 63, w = threadIdx.x >> 6;
    int wr = (w >> 1) * 64, wc = (w & 1) * 64;
    int l16 = lane & 15, lk = lane >> 4;
    #pragma unroll
    for (int j = 0; j < 4; ++j) {
        int n = n0 + wc + j * 16 + l16;
        float bias = blm[n];
        #pragma unroll
        for (int i = 0; i < 4; ++i) {
            #pragma unroll
            for (int r = 0; r < 4; ++r) {
                int m = m0 + wr + i * 16 + lk * 4 + r;
                if (m < B_ * NMASK_)
                    out[(size_t)m * V_ + n] = acc[i][j][r] + bias;
            }
        }
    }
}

// ---------------- Flash-style MFMA attention (unchanged, green) ----------------
__global__ __launch_bounds__(256, 4)
void k_attn_mfma(const ushortT* __restrict__ qb, const ushortT* __restrict__ kb,
                 const ushortT* __restrict__ vt, const int* __restrict__ attn_mask,
                 float* __restrict__ x2) {
    int blk = blockIdx.x;
    int qt = blk & 3, bh = blk >> 2;
    int b = bh / H_, h = bh % H_;
    int tid = threadIdx.x, lane = tid & 63, w = tid >> 6;
    int l16 = lane & 15, lk = lane >> 4;

    __shared__ ushortT QP[128][72];     // Q tile; reused as P (wave w owns rows w*32..w*32+31)
    __shared__ ushortT Ks[64][72];
    __shared__ ushortT Vts[64][72];     // Vts[d][key]
    __shared__ float mskS[128];

    // ---- stage Q tile (once): 128 rows x 64 cols = 1024 x 16B chunks ----
    const ushortT* Qg = qb + ((size_t)bh * T_ + qt * 128) * HS_;
    #pragma unroll
    for (int i = 0; i < 4; ++i) {
        int slot = tid + i * 256;            // 0..1023
        int r = slot >> 3, c8 = (slot & 7) * 8;
        *(u32x4*)(&QP[r][c8]) = *(const u32x4*)(Qg + (size_t)r * HS_ + c8);
    }
    if (tid < 128)
        mskS[tid] = attn_mask[b * T_ + qt * 128 + tid] ? 0.125f : 0.0f;
    __syncthreads();

    // ---- hoist Q fragments + per-row mask ----
    short8 aq[2][2];
    #pragma unroll
    for (int i = 0; i < 2; ++i)
        #pragma unroll
        for (int ks = 0; ks < 2; ++ks)
            aq[i][ks] = *(const short8*)(&QP[w * 32 + i * 16 + l16][ks * 32 + lk * 8]);
    float mrow[2][4];
    #pragma unroll
    for (int i = 0; i < 2; ++i)
        #pragma unroll
        for (int r = 0; r < 4; ++r)
            mrow[i][r] = mskS[w * 32 + i * 16 + lk * 4 + r];
    __syncthreads();   // everyone done reading Q region before P writes

    float lsum[2][4];
    f32x4 accO[2][4];
    #pragma unroll
    for (int i = 0; i < 2; ++i)
        #pragma unroll
        for (int r = 0; r < 4; ++r) lsum[i][r] = 0.f;
    #pragma unroll
    for (int i = 0; i < 2; ++i)
        #pragma unroll
        for (int j = 0; j < 4; ++j)
            accO[i][j] = (f32x4){0.f, 0.f, 0.f, 0.f};

    for (int kt = 0; kt < 8; ++kt) {
        __syncthreads();
        // ---- stage K tile [key][d] and Vt tile [d][key], both coalesced ----
        #pragma unroll
        for (int i = 0; i < 2; ++i) {
            int slot = tid + i * 256;
            int r = slot >> 3, c8 = (slot & 7) * 8;
            *(u32x4*)(&Ks[r][c8]) =
                *(const u32x4*)(kb + ((size_t)bh * T_ + kt * 64 + r) * HS_ + c8);
            *(u32x4*)(&Vts[r][c8]) =
                *(const u32x4*)(vt + ((size_t)bh * HS_ + r) * T_ + kt * 64 + c8);
        }
        __syncthreads();

        // ---- S = Q K^T (per wave: 32 q x 64 k) ----
        f32x4 accS[2][4];
        #pragma unroll
        for (int i = 0; i < 2; ++i)
            #pragma unroll
            for (int j = 0; j < 4; ++j)
                accS[i][j] = (f32x4){0.f, 0.f, 0.f, 0.f};
        #pragma unroll
        for (int ks = 0; ks < 2; ++ks) {
            short8 bk[4];
            #pragma unroll
            for (int j = 0; j < 4; ++j)
                bk[j] = *(const short8*)(&Ks[j * 16 + l16][ks * 32 + lk * 8]);
            #pragma unroll
            for (int i = 0; i < 2; ++i)
                #pragma unroll
                for (int j = 0; j < 4; ++j)
                    accS[i][j] = __builtin_amdgcn_mfma_f32_16x16x32_bf16(aq[i][ks], bk[j], accS[i][j], 0, 0, 0);
        }

        // ---- p = exp(s*msk); lane-local sum; P -> LDS (wave-private rows of QP) ----
        #pragma unroll
        for (int i = 0; i < 2; ++i) {
            #pragma unroll
            for (int r = 0; r < 4; ++r) {
                int rowl = i * 16 + lk * 4 + r;
                float m = mrow[i][r];
                float p0 = __expf(accS[i][0][r] * m);
                float p1 = __expf(accS[i][1][r] * m);
                float p2 = __expf(accS[i][2][r] * m);
                float p3 = __expf(accS[i][3][r] * m);
                lsum[i][r] += (p0 + p1) + (p2 + p3);
                QP[w * 32 + rowl][0 * 16 + l16] = f2bu(p0);
                QP[w * 32 + rowl][1 * 16 + l16] = f2bu(p1);
                QP[w * 32 + rowl][2 * 16 + l16] = f2bu(p2);
                QP[w * 32 + rowl][3 * 16 + l16] = f2bu(p3);
            }
        }

        // ---- O += P V ----
        #pragma unroll
        for (int ks2 = 0; ks2 < 2; ++ks2) {
            short8 ap[2], bv[4];
            #pragma unroll
            for (int i = 0; i < 2; ++i)
                ap[i] = *(const short8*)(&QP[w * 32 + i * 16 + l16][ks2 * 32 + lk * 8]);
            #pragma unroll
            for (int j = 0; j < 4; ++j)
                bv[j] = *(const short8*)(&Vts[j * 16 + l16][ks2 * 32 + lk * 8]);
            #pragma unroll
            for (int i = 0; i < 2; ++i)
                #pragma unroll
                for (int j = 0; j < 4; ++j)
                    accO[i][j] = __builtin_amdgcn_mfma_f32_16x16x32_bf16(ap[i], bv[j], accO[i][j], 0, 0, 0);
        }
    }

    // ---- epilogue: one row-sum reduce, normalize, write x2 (f32) ----
    #pragma unroll
    for (int i = 0; i < 2; ++i) {
        #pragma unroll
        for (int r = 0; r < 4; ++r) {
            float s = lsum[i][r];
            #pragma unroll
            for (int off = 1; off < 16; off <<= 1)
                s += __shfl_xor(s, off);
            float inv = 1.0f / s;
            int t = qt * 128 + w * 32 + i * 16 + lk * 4 + r;
            float* outp = x2 + ((size_t)b * T_ + t) * D_ + h * HS_;
            #pragma unroll
            for (int j = 0; j < 4; ++j)
                outp[j * 16 + l16] = accO[i][j][r] * inv;
        }
    }
}

// ---------------- Classifier head ----------------
__global__ void k_cls(const float* __restrict__ x2, const float* __restrict__ Wc,
                      const float* __restrict__ bc, float* __restrict__ out) {
    int i = threadIdx.x;
    if (i >= B_ * 2) return;
    int b = i >> 1, c = i & 1;
    float acc = bc[c];
    for (int d = 0; d < D_; ++d)
        acc += x2[(size_t)b * T_ * D_ + d] * Wc[d * 2 + c];
    out[i] = acc;
}

extern "C" void kernel_launch(void* const* d_in, const int* in_sizes, int n_in,
                              void* d_out, int out_size, void* d_ws, size_t ws_size,
                              hipStream_t stream) {
    const int* seq        = (const int*)d_in[0];
    const int* seg        = (const int*)d_in[1];
    const int* attn_mask  = (const int*)d_in[2];
    const int* masked_pos = (const int*)d_in[3];
    const float* tok  = (const float*)d_in[4];
    const float* sege = (const float*)d_in[5];
    const float* pos  = (const float*)d_in[6];
    const float* ln_g = (const float*)d_in[7];
    const float* ln_b = (const float*)d_in[8];
    const float* Wq   = (const float*)d_in[9];
    const float* Wk   = (const float*)d_in[10];
    const float* Wv   = (const float*)d_in[11];
    const float* Wlm  = (const float*)d_in[12];
    const float* blm  = (const float*)d_in[13];
    const float* Wc   = (const float*)d_in[14];
    const float* bc   = (const float*)d_in[15];

    float* out_lm  = (float*)d_out;                       // [B, NMASK, V]
    float* out_cls = out_lm + (size_t)B_ * NMASK_ * V_;   // [B, 2]

    const size_t XSZ = (size_t)B_ * T_ * D_;              // 6,291,456
    float* ws = (float*)d_ws;
    float*   x2   = ws;                                   // f32, 25.2 MB
    ushortT* base = (ushortT*)(ws + XSZ);                 // bf16 region
    ushortT* xb    = base;                                // [8192][768]
    ushortT* qb    = base + XSZ;                          // [bh][t][64]
    ushortT* kb    = base + 2 * XSZ;                      // [bh][t][64]
    ushortT* vt    = base + 3 * XSZ;                      // [bh][64][512]  (pre-transposed V)
    ushortT* WcatT = base + 4 * XSZ;                      // [2304][768]
    // After attention, xb/qb/kb/vt/WcatT are dead; reuse for LM buffers:
    ushortT* WlmT  = base;                                // [32000][768]
    ushortT* xm    = base + (size_t)V_ * D_;              // [384][768]

    k_embed_ln<<<B_ * T_, 256, 0, stream>>>(seq, seg, tok, sege, pos, ln_g, ln_b, xb);
    k_prep_wqkv<<<3 * H_, 256, 0, stream>>>(Wq, Wk, Wv, WcatT);
    k_gemm_qkv<<<dim3(18, 64), 256, 0, stream>>>(xb, WcatT, qb, kb, vt);
    k_attn_mfma<<<192 * 4, 256, 0, stream>>>(qb, kb, vt, attn_mask, x2);
    k_transpose_lm<<<dim3(V_ / 64, D_ / 64), 256, 0, stream>>>(Wlm, WlmT);
    k_gather_xm<<<384, 256, 0, stream>>>(x2, masked_pos, xm);
    k_gemm_lm<<<dim3(3, 250), 256, 0, stream>>>(xm, WlmT, blm, out_lm);
    k_cls<<<1, 64, 0, stream>>>(x2, Wc, bc, out_cls);
}

// Round 9
// 232.415 us; speedup vs baseline: 1.0055x; 1.0055x over previous
//
#include <hip/hip_runtime.h>
#include <hip/hip_bf16.h>

#define V_     32000
#define NSEG_  2
#define MAXLEN_ 512
#define D_     768
#define H_     12
#define HS_    64
#define B_     16
#define T_     512
#define NMASK_ 20
#define LN_EPS_ 1e-5f

typedef __hip_bfloat16 bf16;
typedef unsigned short ushortT;
typedef __attribute__((ext_vector_type(8))) short short8;
typedef __attribute__((ext_vector_type(4))) float f32x4;
typedef __attribute__((ext_vector_type(4))) unsigned int u32x4;

__device__ __forceinline__ ushortT f2bu(float f) {
    bf16 h = __float2bfloat16(f);
    return *reinterpret_cast<ushortT*>(&h);
}

// ---------------- Kernel 1: embedding gather + LayerNorm -> xb (bf16) ----------------
__global__ void k_embed_ln(const int* __restrict__ seq, const int* __restrict__ seg,
                           const float* __restrict__ tok, const float* __restrict__ sege,
                           const float* __restrict__ pos, const float* __restrict__ g,
                           const float* __restrict__ bb, ushortT* __restrict__ xb) {
    int row = blockIdx.x;          // b*T + t
    int t = row % T_;
    int tid = threadIdx.x;
    __shared__ float sbuf[D_];
    __shared__ float wsum[4], wsq[4];

    int sidx = seq[row];
    int gidx = seg[row];

    float lsum = 0.f, lsq = 0.f;
    for (int j = tid; j < D_; j += 256) {
        float e = tok[(size_t)sidx * D_ + j] + sege[(size_t)gidx * D_ + j] + pos[(size_t)t * D_ + j];
        sbuf[j] = e;
        lsum += e;
        lsq  += e * e;
    }
    #pragma unroll
    for (int o = 32; o > 0; o >>= 1) {
        lsum += __shfl_down(lsum, o);
        lsq  += __shfl_down(lsq, o);
    }
    if ((tid & 63) == 0) { wsum[tid >> 6] = lsum; wsq[tid >> 6] = lsq; }
    __syncthreads();
    float s  = wsum[0] + wsum[1] + wsum[2] + wsum[3];
    float sq = wsq[0] + wsq[1] + wsq[2] + wsq[3];
    float mean = s * (1.0f / D_);
    float var  = sq * (1.0f / D_) - mean * mean;
    float rstd = rsqrtf(var + LN_EPS_);
    for (int j = tid; j < D_; j += 256) {
        xb[(size_t)row * D_ + j] = f2bu((sbuf[j] - mean) * rstd * g[j] + bb[j]);
    }
}

// ---------------- Prep: WcatT[n][k] bf16, n = which*768 + h*64 + s ----------------
__global__ void k_prep_wqkv(const float* __restrict__ Wq, const float* __restrict__ Wk,
                            const float* __restrict__ Wv, ushortT* __restrict__ Wt) {
    int blk = blockIdx.x;
    int which = blk / H_, h = blk % H_;
    const float* W = (which == 0) ? Wq : (which == 1) ? Wk : Wv;  // [H][D][HS]
    __shared__ float tile[64][65];
    int tid = threadIdx.x, c = tid & 63, rgrp = tid >> 6;
    for (int kc = 0; kc < D_; kc += 64) {
        for (int kk = rgrp; kk < 64; kk += 4)
            tile[kk][c] = W[((size_t)h * D_ + kc + kk) * HS_ + c];
        __syncthreads();
        for (int ss = rgrp; ss < 64; ss += 4)
            Wt[((size_t)which * D_ + h * HS_ + ss) * D_ + kc + c] = f2bu(tile[c][ss]);
        __syncthreads();
    }
}

// ---------------- Prep: WlmT[v][d] bf16 from Wlm[d][v] f32 ----------------
__global__ void k_transpose_lm(const float* __restrict__ W, ushortT* __restrict__ Wt) {
    __shared__ float tile[64][65];
    int v0 = blockIdx.x * 64, d0 = blockIdx.y * 64;
    int tid = threadIdx.x, c = tid & 63;
    for (int rr = tid >> 6; rr < 64; rr += 4)
        tile[rr][c] = W[(size_t)(d0 + rr) * V_ + v0 + c];
    __syncthreads();
    for (int rr = tid >> 6; rr < 64; rr += 4)
        Wt[(size_t)(v0 + rr) * D_ + d0 + c] = f2bu(tile[c][rr]);
}

// ---------------- Prep: gather masked rows -> xm[384][768] bf16 (zero pad) ----------------
__global__ void k_gather_xm(const float* __restrict__ x2, const int* __restrict__ masked_pos,
                            ushortT* __restrict__ xm) {
    int r = blockIdx.x;      // 0..383
    int tid = threadIdx.x;
    if (r < B_ * NMASK_) {
        int b = r / NMASK_, m = r % NMASK_;
        int t = masked_pos[b * NMASK_ + m];
        for (int d = tid; d < D_; d += 256)
            xm[(size_t)r * D_ + d] = f2bu(x2[((size_t)b * T_ + t) * D_ + d]);
    } else {
        for (int d = tid; d < D_; d += 256)
            xm[(size_t)r * D_ + d] = 0;
    }
}

// ---------------- 3-buffer depth-2 pipelined MFMA 128x128 GEMM body ----------------
// Per K-step: vmcnt(4) [tile t landed, tile t+1 stays in flight] -> barrier ->
// stage(t+2) -> ds_read+MFMA(t). Never drains to vmcnt(0) until the last step.
// LDS: 3 buffers x (As 4096 + Bs 4096) ushorts = 48 KB -> 3 blocks/CU.
__device__ __forceinline__ void stage_tile(const ushortT* __restrict__ A,
                                           const ushortT* __restrict__ Bt,
                                           int m0, int n0, int k0,
                                           ushortT* buf, int w, int lane) {
    #pragma unroll
    for (int i = 0; i < 2; ++i) {
        int slot = w * 64 + lane + i * 256;    // 0..511 (16B chunks)
        int row = slot >> 2, col = (slot & 3) * 8;
        __builtin_amdgcn_global_load_lds(
            (const __attribute__((address_space(1))) void*)(A + (size_t)(m0 + row) * D_ + k0 + col),
            (__attribute__((address_space(3))) void*)(buf + (w * 64 + i * 256) * 8),
            16, 0, 0);
        __builtin_amdgcn_global_load_lds(
            (const __attribute__((address_space(1))) void*)(Bt + (size_t)(n0 + row) * D_ + k0 + col),
            (__attribute__((address_space(3))) void*)(buf + 4096 + (w * 64 + i * 256) * 8),
            16, 0, 0);
    }
}

__device__ __forceinline__ void compute_step(const ushortT* Asc, const ushortT* Bsc,
                                             int wr, int wc, int l16, int lk,
                                             f32x4 acc[4][4]) {
    short8 a[4], bfr[4];
    #pragma unroll
    for (int i = 0; i < 4; ++i) {
        a[i]   = *(const short8*)(Asc + (wr + i * 16 + l16) * 32 + lk * 8);
        bfr[i] = *(const short8*)(Bsc + (wc + i * 16 + l16) * 32 + lk * 8);
    }
    #pragma unroll
    for (int i = 0; i < 4; ++i)
        #pragma unroll
        for (int j = 0; j < 4; ++j)
            acc[i][j] = __builtin_amdgcn_mfma_f32_16x16x32_bf16(a[i], bfr[j], acc[i][j], 0, 0, 0);
}

__device__ __forceinline__ void gemm128_pipe(const ushortT* __restrict__ A,
                                             const ushortT* __restrict__ Bt,
                                             int m0, int n0,
                                             ushortT* lds,       // 24576 ushorts (48 KB)
                                             f32x4 acc[4][4]) {
    const int NT = D_ / 32;   // 24
    int tid = threadIdx.x;
    int lane = tid & 63, w = tid >> 6;
    int wr = (w >> 1) * 64, wc = (w & 1) * 64;
    int l16 = lane & 15, lk = lane >> 4;

    #pragma unroll
    for (int i = 0; i < 4; ++i)
        #pragma unroll
        for (int j = 0; j < 4; ++j)
            acc[i][j] = (f32x4){0.f, 0.f, 0.f, 0.f};

    // prologue: two tiles in flight
    stage_tile(A, Bt, m0, n0, 0,  lds,        w, lane);
    stage_tile(A, Bt, m0, n0, 32, lds + 8192, w, lane);

    for (int t = 0; t < NT - 1; ++t) {
        // tile t's 4 per-wave loads landed; tile t+1's 4 remain in flight
        asm volatile("s_waitcnt vmcnt(4)" ::: "memory");
        __builtin_amdgcn_s_barrier();
        __builtin_amdgcn_sched_barrier(0);
        if (t + 2 < NT)
            stage_tile(A, Bt, m0, n0, (t + 2) * 32, lds + ((t + 2) % 3) * 8192, w, lane);
        const ushortT* Asc = lds + (t % 3) * 8192;
        compute_step(Asc, Asc + 4096, wr, wc, l16, lk, acc);
    }
    // last tile: drain fully
    asm volatile("s_waitcnt vmcnt(0)" ::: "memory");
    __builtin_amdgcn_s_barrier();
    __builtin_amdgcn_sched_barrier(0);
    const ushortT* Asc = lds + ((NT - 1) % 3) * 8192;
    compute_step(Asc, Asc + 4096, wr, wc, l16, lk, acc);
}

// ---------------- QKV GEMM: [8192 x 2304]; V written pre-transposed vt[bh][d][t] ----------------
__global__ __launch_bounds__(256, 3)
void k_gemm_qkv(const ushortT* __restrict__ xb, const ushortT* __restrict__ WcatT,
                ushortT* __restrict__ qb, ushortT* __restrict__ kb,
                ushortT* __restrict__ vt) {
    __shared__ ushortT lds[24576];
    f32x4 acc[4][4];
    int n0 = blockIdx.x * 128, m0 = blockIdx.y * 128;
    gemm128_pipe(xb, WcatT, m0, n0, lds, acc);

    int lane = threadIdx.x & 63, w = threadIdx.x >> 6;
    int wr = (w >> 1) * 64, wc = (w & 1) * 64;
    int l16 = lane & 15, lk = lane >> 4;
    #pragma unroll
    for (int j = 0; j < 4; ++j) {
        int n = n0 + wc + j * 16 + l16;
        int which = n / D_;          // uniform per block (128 | 768)
        int rem = n - which * D_;
        int h = rem >> 6, s = rem & 63;
        #pragma unroll
        for (int i = 0; i < 4; ++i) {
            #pragma unroll
            for (int r = 0; r < 4; ++r) {
                int m = m0 + wr + i * 16 + lk * 4 + r;
                int b = m >> 9, t = m & (T_ - 1);
                if (which == 2) {
                    vt[((size_t)(b * H_ + h) * HS_ + s) * T_ + t] = f2bu(acc[i][j][r]);
                } else {
                    ushortT* outp = (which == 0) ? qb : kb;
                    outp[((size_t)(b * H_ + h) * T_ + t) * HS_ + s] = f2bu(acc[i][j][r]);
                }
            }
        }
    }
}

// ---------------- LM GEMM: [384 x 32000] ----------------
__global__ __launch_bounds__(256, 3)
void k_gemm_lm(const ushortT* __restrict__ xm, const ushortT* __restrict__ WlmT,
               const float* __restrict__ blm, float* __restrict__ out) {
    __shared__ ushortT lds[24576];
    f32x4 acc[4][4];
    int m0 = blockIdx.x * 128, n0 = blockIdx.y * 128;
    gemm128_pipe(xm, WlmT, m0, n0, lds, acc);

    int lane = threadIdx.x & 63, w = threadIdx.x >> 6;
    int wr = (w >> 1) * 64, wc = (w & 1) * 64;
    int l16 = lane & 15, lk = lane >> 4;
    #pragma unroll
    for (int j = 0; j < 4; ++j) {
        int n = n0 + wc + j * 16 + l16;
        float bias = blm[n];
        #pragma unroll
        for (int i = 0; i < 4; ++i) {
            #pragma unroll
            for (int r = 0; r < 4; ++r) {
                int m = m0 + wr + i * 16 + lk * 4 + r;
                if (m < B_ * NMASK_)
                    out[(size_t)m * V_ + n] = acc[i][j][r] + bias;
            }
        }
    }
}

// ---------------- Flash-style MFMA attention (unchanged, green) ----------------
__global__ __launch_bounds__(256, 4)
void k_attn_mfma(const ushortT* __restrict__ qb, const ushortT* __restrict__ kb,
                 const ushortT* __restrict__ vt, const int* __restrict__ attn_mask,
                 float* __restrict__ x2) {
    int blk = blockIdx.x;
    int qt = blk & 3, bh = blk >> 2;
    int b = bh / H_, h = bh % H_;
    int tid = threadIdx.x, lane = tid & 63, w = tid >> 6;
    int l16 = lane & 15, lk = lane >> 4;

    __shared__ ushortT QP[128][72];     // Q tile; reused as P (wave w owns rows w*32..w*32+31)
    __shared__ ushortT Ks[64][72];
    __shared__ ushortT Vts[64][72];     // Vts[d][key]
    __shared__ float mskS[128];

    // ---- stage Q tile (once): 128 rows x 64 cols = 1024 x 16B chunks ----
    const ushortT* Qg = qb + ((size_t)bh * T_ + qt * 128) * HS_;
    #pragma unroll
    for (int i = 0; i < 4; ++i) {
        int slot = tid + i * 256;            // 0..1023
        int r = slot >> 3, c8 = (slot & 7) * 8;
        *(u32x4*)(&QP[r][c8]) = *(const u32x4*)(Qg + (size_t)r * HS_ + c8);
    }
    if (tid < 128)
        mskS[tid] = attn_mask[b * T_ + qt * 128 + tid] ? 0.125f : 0.0f;
    __syncthreads();

    // ---- hoist Q fragments + per-row mask ----
    short8 aq[2][2];
    #pragma unroll
    for (int i = 0; i < 2; ++i)
        #pragma unroll
        for (int ks = 0; ks < 2; ++ks)
            aq[i][ks] = *(const short8*)(&QP[w * 32 + i * 16 + l16][ks * 32 + lk * 8]);
    float mrow[2][4];
    #pragma unroll
    for (int i = 0; i < 2; ++i)
        #pragma unroll
        for (int r = 0; r < 4; ++r)
            mrow[i][r] = mskS[w * 32 + i * 16 + lk * 4 + r];
    __syncthreads();   // everyone done reading Q region before P writes

    float lsum[2][4];
    f32x4 accO[2][4];
    #pragma unroll
    for (int i = 0; i < 2; ++i)
        #pragma unroll
        for (int r = 0; r < 4; ++r) lsum[i][r] = 0.f;
    #pragma unroll
    for (int i = 0; i < 2; ++i)
        #pragma unroll
        for (int j = 0; j < 4; ++j)
            accO[i][j] = (f32x4){0.f, 0.f, 0.f, 0.f};

    for (int kt = 0; kt < 8; ++kt) {
        __syncthreads();
        // ---- stage K tile [key][d] and Vt tile [d][key], both coalesced ----
        #pragma unroll
        for (int i = 0; i < 2; ++i) {
            int slot = tid + i * 256;
            int r = slot >> 3, c8 = (slot & 7) * 8;
            *(u32x4*)(&Ks[r][c8]) =
                *(const u32x4*)(kb + ((size_t)bh * T_ + kt * 64 + r) * HS_ + c8);
            *(u32x4*)(&Vts[r][c8]) =
                *(const u32x4*)(vt + ((size_t)bh * HS_ + r) * T_ + kt * 64 + c8);
        }
        __syncthreads();

        // ---- S = Q K^T (per wave: 32 q x 64 k) ----
        f32x4 accS[2][4];
        #pragma unroll
        for (int i = 0; i < 2; ++i)
            #pragma unroll
            for (int j = 0; j < 4; ++j)
                accS[i][j] = (f32x4){0.f, 0.f, 0.f, 0.f};
        #pragma unroll
        for (int ks = 0; ks < 2; ++ks) {
            short8 bk[4];
            #pragma unroll
            for (int j = 0; j < 4; ++j)
                bk[j] = *(const short8*)(&Ks[j * 16 + l16][ks * 32 + lk * 8]);
            #pragma unroll
            for (int i = 0; i < 2; ++i)
                #pragma unroll
                for (int j = 0; j < 4; ++j)
                    accS[i][j] = __builtin_amdgcn_mfma_f32_16x16x32_bf16(aq[i][ks], bk[j], accS[i][j], 0, 0, 0);
        }

        // ---- p = exp(s*msk); lane-local sum; P -> LDS (wave-private rows of QP) ----
        #pragma unroll
        for (int i = 0; i < 2; ++i) {
            #pragma unroll
            for (int r = 0; r < 4; ++r) {
                int rowl = i * 16 + lk * 4 + r;
                float m = mrow[i][r];
                float p0 = __expf(accS[i][0][r] * m);
                float p1 = __expf(accS[i][1][r] * m);
                float p2 = __expf(accS[i][2][r] * m);
                float p3 = __expf(accS[i][3][r] * m);
                lsum[i][r] += (p0 + p1) + (p2 + p3);
                QP[w * 32 + rowl][0 * 16 + l16] = f2bu(p0);
                QP[w * 32 + rowl][1 * 16 + l16] = f2bu(p1);
                QP[w * 32 + rowl][2 * 16 + l16] = f2bu(p2);
                QP[w * 32 + rowl][3 * 16 + l16] = f2bu(p3);
            }
        }

        // ---- O += P V ----
        #pragma unroll
        for (int ks2 = 0; ks2 < 2; ++ks2) {
            short8 ap[2], bv[4];
            #pragma unroll
            for (int i = 0; i < 2; ++i)
                ap[i] = *(const short8*)(&QP[w * 32 + i * 16 + l16][ks2 * 32 + lk * 8]);
            #pragma unroll
            for (int j = 0; j < 4; ++j)
                bv[j] = *(const short8*)(&Vts[j * 16 + l16][ks2 * 32 + lk * 8]);
            #pragma unroll
            for (int i = 0; i < 2; ++i)
                #pragma unroll
                for (int j = 0; j < 4; ++j)
                    accO[i][j] = __builtin_amdgcn_mfma_f32_16x16x32_bf16(ap[i], bv[j], accO[i][j], 0, 0, 0);
        }
    }

    // ---- epilogue: one row-sum reduce, normalize, write x2 (f32) ----
    #pragma unroll
    for (int i = 0; i < 2; ++i) {
        #pragma unroll
        for (int r = 0; r < 4; ++r) {
            float s = lsum[i][r];
            #pragma unroll
            for (int off = 1; off < 16; off <<= 1)
                s += __shfl_xor(s, off);
            float inv = 1.0f / s;
            int t = qt * 128 + w * 32 + i * 16 + lk * 4 + r;
            float* outp = x2 + ((size_t)b * T_ + t) * D_ + h * HS_;
            #pragma unroll
            for (int j = 0; j < 4; ++j)
                outp[j * 16 + l16] = accO[i][j][r] * inv;
        }
    }
}

// ---------------- Classifier head ----------------
__global__ void k_cls(const float* __restrict__ x2, const float* __restrict__ Wc,
                      const float* __restrict__ bc, float* __restrict__ out) {
    int i = threadIdx.x;
    if (i >= B_ * 2) return;
    int b = i >> 1, c = i & 1;
    float acc = bc[c];
    for (int d = 0; d < D_; ++d)
        acc += x2[(size_t)b * T_ * D_ + d] * Wc[d * 2 + c];
    out[i] = acc;
}

extern "C" void kernel_launch(void* const* d_in, const int* in_sizes, int n_in,
                              void* d_out, int out_size, void* d_ws, size_t ws_size,
                              hipStream_t stream) {
    const int* seq        = (const int*)d_in[0];
    const int* seg        = (const int*)d_in[1];
    const int* attn_mask  = (const int*)d_in[2];
    const int* masked_pos = (const int*)d_in[3];
    const float* tok  = (const float*)d_in[4];
    const float* sege = (const float*)d_in[5];
    const float* pos  = (const float*)d_in[6];
    const float* ln_g = (const float*)d_in[7];
    const float* ln_b = (const float*)d_in[8];
    const float* Wq   = (const float*)d_in[9];
    const float* Wk   = (const float*)d_in[10];
    const float* Wv   = (const float*)d_in[11];
    const float* Wlm  = (const float*)d_in[12];
    const float* blm  = (const float*)d_in[13];
    const float* Wc   = (const float*)d_in[14];
    const float* bc   = (const float*)d_in[15];

    float* out_lm  = (float*)d_out;                       // [B, NMASK, V]
    float* out_cls = out_lm + (size_t)B_ * NMASK_ * V_;   // [B, 2]

    const size_t XSZ = (size_t)B_ * T_ * D_;              // 6,291,456
    float* ws = (float*)d_ws;
    float*   x2   = ws;                                   // f32, 25.2 MB
    ushortT* base = (ushortT*)(ws + XSZ);                 // bf16 region
    ushortT* xb    = base;                                // [8192][768]
    ushortT* qb    = base + XSZ;                          // [bh][t][64]
    ushortT* kb    = base + 2 * XSZ;                      // [bh][t][64]
    ushortT* vt    = base + 3 * XSZ;                      // [bh][64][512]  (pre-transposed V)
    ushortT* WcatT = base + 4 * XSZ;                      // [2304][768]
    // After attention, xb/qb/kb/vt/WcatT are dead; reuse for LM buffers:
    ushortT* WlmT  = base;                                // [32000][768]
    ushortT* xm    = base + (size_t)V_ * D_;              // [384][768]

    k_embed_ln<<<B_ * T_, 256, 0, stream>>>(seq, seg, tok, sege, pos, ln_g, ln_b, xb);
    k_prep_wqkv<<<3 * H_, 256, 0, stream>>>(Wq, Wk, Wv, WcatT);
    k_gemm_qkv<<<dim3(18, 64), 256, 0, stream>>>(xb, WcatT, qb, kb, vt);
    k_attn_mfma<<<192 * 4, 256, 0, stream>>>(qb, kb, vt, attn_mask, x2);
    k_transpose_lm<<<dim3(V_ / 64, D_ / 64), 256, 0, stream>>>(Wlm, WlmT);
    k_gather_xm<<<384, 256, 0, stream>>>(x2, masked_pos, xm);
    k_gemm_lm<<<dim3(3, 250), 256, 0, stream>>>(xm, WlmT, blm, out_lm);
    k_cls<<<1, 64, 0, stream>>>(x2, Wc, bc, out_cls);
}